// Round 5
// baseline (81.468 us; speedup 1.0000x reference)
//
#include <hip/hip_runtime.h>
#include <hip/hip_bf16.h>
#include <math.h>

// Shapes (fixed): B=1, N=4 views (V=5 incl. target), HW=1024, D=32, C=128,
// IN_DIM = 326, NUM_FREQS = 16, RES = 32.
// Grid: 2 blocks per h (d-halves of 16), 256 threads each.
#define XH 1024
#define XD 32
#define XC 128
#define XK 326

typedef __attribute__((ext_vector_type(8))) short bf16x8;
typedef __attribute__((ext_vector_type(4))) float f32x4;

__device__ __forceinline__ unsigned short f2b(float f) {
  unsigned u = __float_as_uint(f);
  return (unsigned short)((u + 0x7FFFu + ((u >> 16) & 1u)) >> 16);
}
__device__ __forceinline__ float b2f(unsigned short b) {
  return __uint_as_float(((unsigned)b) << 16);
}
__device__ __forceinline__ unsigned pk2bf(float v0, float v1) {
  __hip_bfloat162 h = __float22bfloat162_rn(make_float2(v0, v1));  // v_cvt_pk_bf16_f32
  return *reinterpret_cast<unsigned*>(&h);
}

// ws fragment tables (bf16 hi/lo split, B-operand lane layout for
// mfma_f32_16x16x32_bf16). frag element: lane l, j: B[k][c],
// k = kc*32 + 8*(l>>4) + j, c = ct*16 + (l&15).
// W1 padded K 326 -> 384 (12 kc); W2 K=128 (4 kc).
#define WT1 (12 * 8 * 64)   // 6144 fraglanes
#define WT2 (4 * 8 * 64)    // 2048 fraglanes

__global__ void prep_frags(const float* __restrict__ W1,
                           const float* __restrict__ W2,
                           unsigned int* __restrict__ ws) {
  int f = blockIdx.x * 256 + threadIdx.x;   // 0..8191
  if (f >= WT1 + WT2) return;
  const float* W; int KMAX; int fl; size_t hoff, loff;
  if (f < WT1) { W = W1; KMAX = XK; fl = f; hoff = 0; loff = WT1; }
  else { W = W2; KMAX = XC; fl = f - WT1; hoff = 2 * (size_t)WT1; loff = 2 * (size_t)WT1 + WT2; }
  int l = fl & 63, ct = (fl >> 6) & 7, kc = fl >> 9;
  int c = ct * 16 + (l & 15);
  int kbase = kc * 32 + 8 * (l >> 4);
  unsigned hi[4], lo[4];
  #pragma unroll
  for (int jj = 0; jj < 4; ++jj) {
    int k0 = kbase + 2 * jj;
    float w0 = (k0     < KMAX) ? W[k0 * XC + c]       : 0.f;
    float w1 = (k0 + 1 < KMAX) ? W[(k0 + 1) * XC + c] : 0.f;
    unsigned short h0 = f2b(w0); unsigned short l0 = f2b(w0 - b2f(h0));
    unsigned short h1 = f2b(w1); unsigned short l1 = f2b(w1 - b2f(h1));
    hi[jj] = (unsigned)h0 | ((unsigned)h1 << 16);
    lo[jj] = (unsigned)l0 | ((unsigned)l1 << 16);
  }
  uint4 vh; vh.x = hi[0]; vh.y = hi[1]; vh.z = hi[2]; vh.w = hi[3];
  uint4 vl; vl.x = lo[0]; vl.y = lo[1]; vl.z = lo[2]; vl.w = lo[3];
  *(uint4*)(ws + (hoff + fl) * 4) = vh;
  *(uint4*)(ws + (loff + fl) * 4) = vl;
}

// LDS layout (uMem = 32 KB):
//   sFcHi [64][128] bf16 at uMem+0       (GEMM1 A hi, kq 0..127, 64 rows)
//   sFcLo [64][128] bf16 at uMem+16384
//   hb hi [16][128] + lo [16][128] reuse uMem+16384 after GEMM1.
//   sOut  [16][129] f32 reuses uMem+0 after GEMM1.
//   swizzle (ushort idx): i ^ ((row&7)<<3)
// GEMM1 row order: lds_row = ld*4 + n  (ld = block-local depth 0..15).
// kq 128..351 never touch sFc: A-fragments synthesized in registers (trig) or
// read from the per-n sEnc2 table. kc=11 all-zero -> skipped.

__global__ __launch_bounds__(256, 4)
void nerf_main(const float* __restrict__ xref,   // (4,1024,128)
               const float* __restrict__ mask,   // (4,1024)
               const float* __restrict__ rpts,   // (1024,32,3)
               const float* __restrict__ rays,   // (5,1024,6)
               const float* __restrict__ Rm,     // (5,3,3)
               const float* __restrict__ Tm,     // (5,3)
               const float* __restrict__ focp,   // (5)
               const float* __restrict__ b1p,    // (128)
               const float* __restrict__ b2p,    // (128)
               const float* __restrict__ Wvp,    // (326)
               const float* __restrict__ bvp,    // (1)
               const float* __restrict__ Wdp,    // (128)
               const bf16x8* __restrict__ wfrag, // ws fragment tables
               float* __restrict__ out0,         // (1024,32,129)
               float* __restrict__ out1)         // (4,1024,32)
{
  const int h = blockIdx.x >> 1;
  const int q = blockIdx.x & 1;     // d-half: global d = q*16 + ld
  const int tid = threadIdx.x;

  __shared__ float sR[5][3][3];
  __shared__ float sT[5][3];
  __shared__ float sFoc[5];
  __shared__ float sRay[5][6];
  __shared__ float sOiv[5][3];
  __shared__ float sDiv[5][3];
  __shared__ float sPlk[4][6];
  __shared__ float sOtg[4][3];
  __shared__ float sPv[5][16][3];   // block-local d
  __shared__ float sBc[4][16][4];
  __shared__ int   sBp[4][16][4];
  __shared__ float sWv[XK];
  __shared__ float sAt[16];
  __shared__ float sBt[4];
  __shared__ float sLogit[4][16];
  __shared__ float sAw[4][16];
  __shared__ float sOutPart[4][16];
  // per-n feature table for kq in [224,352): [pv_raw(3, zero here; patched
  // per-d at use), cam_iv_enc(96), d_iv(3), zero-pad(26)]  — bf16
  __shared__ __align__(16) unsigned short sEnc2[4][128];
  __shared__ __align__(16) unsigned char uMem[32768];
  unsigned short* sFcHi = (unsigned short*)uMem;             // [64*128]
  unsigned short* sFcLo = (unsigned short*)(uMem + 16384);   // [64*128]
  unsigned short* sHbHi = (unsigned short*)(uMem + 16384);   // [16*128]
  unsigned short* sHbLo = sHbHi + 16 * 128;                  // [16*128]
  float*          sOut  = (float*)uMem;                      // [16*129]

  // ---- stage small tensors ----
  for (int i = tid; i < 45; i += 256) ((float*)sR)[i] = Rm[i];
  for (int i = tid; i < 15; i += 256) ((float*)sT)[i] = Tm[i];
  for (int i = tid; i < 5;  i += 256) sFoc[i] = focp[i];
  for (int i = tid; i < 30; i += 256) { int v = i / 6, j = i % 6; sRay[v][j] = rays[(v*XH + h)*6 + j]; }
  for (int i = tid; i < XK; i += 256) sWv[i] = Wvp[i];
  __syncthreads();   // B1

  // ---- p_view (block-local d) + o_iv/d_iv ----
  if (tid < 80) {
    int v = tid >> 4, ld = tid & 15, d = q * 16 + ld;
    float p0 = rpts[(h*XD + d)*3 + 0];
    float p1 = rpts[(h*XD + d)*3 + 1];
    float p2 = rpts[(h*XD + d)*3 + 2];
    #pragma unroll
    for (int j = 0; j < 3; ++j)
      sPv[v][ld][j] = p0*sR[v][0][j] + p1*sR[v][1][j] + p2*sR[v][2][j] + sT[v][j];
  } else if (tid < 85) {
    int v = tid - 80;
    #pragma unroll
    for (int j = 0; j < 3; ++j) {
      sOiv[v][j] = sRay[0][0]*sR[v][0][j] + sRay[0][1]*sR[v][1][j] + sRay[0][2]*sR[v][2][j] + sT[v][j];
      sDiv[v][j] = sRay[0][3]*sR[v][0][j] + sRay[0][4]*sR[v][1][j] + sRay[0][5]*sR[v][2][j];
    }
  }
  __syncthreads();   // B2

  // ---- plucker + o_tg + bilinear coefs + sAt ----
  if (tid < 4) {
    int n = tid;
    float d0 = sDiv[n+1][0], d1 = sDiv[n+1][1], d2 = sDiv[n+1][2];
    float inv = 1.f / (sqrtf(d0*d0 + d1*d1 + d2*d2) + 1e-8f);
    float n0 = d0*inv, n1 = d1*inv, n2 = d2*inv;
    float o0 = sOiv[n+1][0], o1 = sOiv[n+1][1], o2 = sOiv[n+1][2];
    sPlk[n][0] = n0; sPlk[n][1] = n1; sPlk[n][2] = n2;
    sPlk[n][3] = o1*n2 - o2*n1;
    sPlk[n][4] = o2*n0 - o0*n2;
    sPlk[n][5] = o0*n1 - o1*n0;
    #pragma unroll
    for (int j = 0; j < 3; ++j)
      sOtg[n][j] = sRay[1+n][0]*sR[0][0][j] + sRay[1+n][1]*sR[0][1][j] + sRay[1+n][2]*sR[0][2][j] + sT[0][j];
  }
  if (tid >= 32 && tid < 96) {
    int idx = tid - 32, n = idx >> 4, ld = idx & 15, v = n + 1;
    float px = sPv[v][ld][0], py = sPv[v][ld][1], pz = sPv[v][ld][2], fo = sFoc[v];
    float gx = -(fo*px)/pz, gy = -(fo*py)/pz;
    if (isnan(gx)) gx = 0.f;
    if (isnan(gy)) gy = 0.f;
    gx = fminf(fmaxf(gx, -1.2f), 1.2f);
    gy = fminf(fmaxf(gy, -1.2f), 1.2f);
    float x = (gx + 1.f)*15.5f, y = (gy + 1.f)*15.5f;
    float x0f = floorf(x), y0f = floorf(y);
    float wx1 = x - x0f, wx0 = 1.f - wx1;
    float wy1 = y - y0f, wy0 = 1.f - wy1;
    int x0i = (int)x0f, y0i = (int)y0f;
    bool vx0 = (x0f >=  0.f) & (x0f <= 31.f);
    bool vx1 = (x0f >= -1.f) & (x0f <= 30.f);
    bool vy0 = (y0f >=  0.f) & (y0f <= 31.f);
    bool vy1 = (y0f >= -1.f) & (y0f <= 30.f);
    int x0c = min(max(x0i, 0), 31), x1c = min(max(x0i + 1, 0), 31);
    int y0c = min(max(y0i, 0), 31), y1c = min(max(y0i + 1, 0), 31);
    int p00 = y0c*32 + x0c, p10 = y0c*32 + x1c, p01 = y1c*32 + x0c, p11 = y1c*32 + x1c;
    sBc[n][ld][0] = wx0*wy0*((vx0 && vy0) ? mask[n*XH + p00] : 0.f);
    sBc[n][ld][1] = wx1*wy0*((vx1 && vy0) ? mask[n*XH + p10] : 0.f);
    sBc[n][ld][2] = wx0*wy1*((vx0 && vy1) ? mask[n*XH + p01] : 0.f);
    sBc[n][ld][3] = wx1*wy1*((vx1 && vy1) ? mask[n*XH + p11] : 0.f);
    sBp[n][ld][0] = p00; sBp[n][ld][1] = p10; sBp[n][ld][2] = p01; sBp[n][ld][3] = p11;
  }
  if (tid >= 128) {
    // sAt: xyz_iv_enc[view 0] . Wv slice (needs only sPv[0], sWv)
    int t = tid - 128;
    int ld = t >> 3, sub = t & 7;
    float p = 0.f;
    for (int kk = sub * 12; kk < sub * 12 + 12; ++kk) {
      int comp = kk >> 5, idx = kk & 31;
      float ang = sPv[0][ld][comp] * (float)(1 << (idx & 15));
      float ev = (idx < 16) ? __sinf(ang) : __cosf(ang);
      p += ev * sWv[128 + kk];
    }
    if (sub == 0)
      for (int j = 0; j < 3; ++j) p += sPv[0][ld][j] * sWv[224 + j];
    #pragma unroll
    for (int o = 1; o < 8; o <<= 1) p += __shfl_xor(p, o);
    if (sub == 0) sAt[ld] = p;
  }
  __syncthreads();   // B3

  // ---- sEnc2 fill (2 slots/thread) + target-origin logit tail ----
  for (int s = tid; s < 512; s += 256) {
    int n = s >> 7, off = s & 127;
    float val = 0.f;
    if (off >= 3 && off < 99) {
      int kk = off - 3;                       // cam_iv_enc index
      int comp = kk >> 4, idx = kk & 15;
      float ang = sPlk[n][comp] * (float)(1 << (idx & 7));
      val = (idx < 8) ? __sinf(ang) : __cosf(ang);
    } else if (off >= 99 && off < 102) {
      val = sDiv[n + 1][off - 99];
    }
    sEnc2[n][off] = f2b(val);
  }
  if (tid >= 224) {
    int t = tid - 224, n = t >> 3, sub = t & 7;
    float p = 0.f;
    for (int kk = sub * 12; kk < sub * 12 + 12; ++kk) {
      int comp = kk >> 5, idx = kk & 31;
      float ang = sOtg[n][comp] * (float)(1 << (idx & 15));
      float ev = (idx < 16) ? __sinf(ang) : __cosf(ang);
      p += ev * sWv[230 + kk];
    }
    if (sub == 0) {
      for (int j = 0; j < 3; ++j) p += sOtg[n][j] * sWv[227 + j];
      p += bvp[0];
    }
    #pragma unroll
    for (int o = 1; o < 8; o <<= 1) p += __shfl_xor(p, o);
    if (sub == 0) sBt[n] = p;
  }
  __syncthreads();   // B4

  // build-thread constants: lds row = ld*4 + n
  const int brow = tid >> 2;            // 0..63
  const int bn = brow & 3, bld = brow >> 2;
  const int kloc0 = (tid & 3) * 16;     // k offset within row
  float plog = 0.f;                     // logit partial (kq 0..127)

  // ======= merged gather: both 64-col chunks -> sFc[64][128] =======
  {
    const float* bc = sBc[bn][bld];
    const int*   bp = sBp[bn][bld];
    const float* xb = xref + bn * XH * XC;
    #pragma unroll
    for (int chunk = 0; chunk < 2; ++chunk) {
      int kg = chunk * 64 + kloc0;
      float vv[16];
      #pragma unroll
      for (int qq = 0; qq < 4; ++qq) {
        float4 a0 = *(const float4*)(xb + bp[0] * XC + kg + 4 * qq);
        float4 a1 = *(const float4*)(xb + bp[1] * XC + kg + 4 * qq);
        float4 a2 = *(const float4*)(xb + bp[2] * XC + kg + 4 * qq);
        float4 a3 = *(const float4*)(xb + bp[3] * XC + kg + 4 * qq);
        #pragma unroll
        for (int j = 0; j < 4; ++j)
          vv[4 * qq + j] = bc[0]*(&a0.x)[j] + bc[1]*(&a1.x)[j]
                         + bc[2]*(&a2.x)[j] + bc[3]*(&a3.x)[j];
      }
      #pragma unroll
      for (int j = 0; j < 16; ++j) plog += vv[j] * sWv[kg + j];
      #pragma unroll
      for (int qq = 0; qq < 2; ++qq) {
        unsigned ph[4], pl[4];
        #pragma unroll
        for (int j = 0; j < 4; ++j) {
          float v0 = vv[8 * qq + 2 * j], v1 = vv[8 * qq + 2 * j + 1];
          unsigned hp = pk2bf(v0, v1);
          float r0 = v0 - b2f((unsigned short)(hp & 0xFFFF));
          float r1 = v1 - b2f((unsigned short)(hp >> 16));
          ph[j] = hp;
          pl[j] = pk2bf(r0, r1);
        }
        int gidx = (brow * 128 + kg + 8 * qq) ^ ((brow & 7) << 3);
        *(uint4*)&sFcHi[gidx] = *(uint4*)ph;
        *(uint4*)&sFcLo[gidx] = *(uint4*)pl;
      }
    }
    // logit partial reduce (4 threads per (n,ld))
    {
      float p = plog;
      p += __shfl_xor(p, 1);
      p += __shfl_xor(p, 2);
      if ((tid & 3) == 0) sLogit[bn][bld] = p;
    }
  }
  __syncthreads();   // B5: sFc + sLogit ready

  // ---- softmax over n ----
  if (tid < 16) {
    int ld = tid, d = q * 16 + ld;
    float l0 = sLogit[0][ld] + sAt[ld] + sBt[0];
    float l1 = sLogit[1][ld] + sAt[ld] + sBt[1];
    float l2 = sLogit[2][ld] + sAt[ld] + sBt[2];
    float l3 = sLogit[3][ld] + sAt[ld] + sBt[3];
    float m = fmaxf(fmaxf(l0, l1), fmaxf(l2, l3));
    float e0 = __expf(l0 - m), e1 = __expf(l1 - m), e2 = __expf(l2 - m), e3 = __expf(l3 - m);
    float inv = 1.f / (e0 + e1 + e2 + e3);
    float w0 = e0*inv, w1 = e1*inv, w2 = e2*inv, w3 = e3*inv;
    sAw[0][ld] = w0; sAw[1][ld] = w1; sAw[2][ld] = w2; sAw[3][ld] = w3;
    out1[(0*XH + h)*XD + d] = w0;
    out1[(1*XH + h)*XD + d] = w1;
    out1[(2*XH + h)*XD + d] = w2;
    out1[(3*XH + h)*XD + d] = w3;
  }

  // ---- wave decomposition for GEMM1: M=64 rows, N=128 ----
  // wave w: row-tile w (rows w*16..w*16+15), all 8 col-tiles.
  const int w = tid >> 6, lane = tid & 63;
  const int lrow = lane & 15, lg = lane >> 4;
  float bias1[8];
  #pragma unroll
  for (int ct = 0; ct < 8; ++ct) bias1[ct] = b1p[ct * 16 + lrow];

  f32x4 acc1[8];
  #pragma unroll
  for (int ct = 0; ct < 8; ++ct) acc1[ct] = (f32x4){0.f, 0.f, 0.f, 0.f};

  // ======= GEMM1 part A: kq 0..127 from LDS (4 kc) =======
  #pragma unroll
  for (int sk = 0; sk < 4; ++sk) {
    const int r0 = w * 16 + lrow;
    const int ai0 = (r0 * 128 + sk * 32 + 8 * lg) ^ ((r0 & 7) << 3);
    bf16x8 ah = *(const bf16x8*)&sFcHi[ai0];
    bf16x8 al = *(const bf16x8*)&sFcLo[ai0];
    const bf16x8* wk = wfrag + (sk * 8) * 64 + lane;
    #pragma unroll
    for (int ct = 0; ct < 8; ++ct) {
      bf16x8 bh = wk[ct * 64];
      bf16x8 bl = wk[WT1 + ct * 64];
      acc1[ct] = __builtin_amdgcn_mfma_f32_16x16x32_bf16(ah, bh, acc1[ct], 0, 0, 0);
      acc1[ct] = __builtin_amdgcn_mfma_f32_16x16x32_bf16(ah, bl, acc1[ct], 0, 0, 0);
      acc1[ct] = __builtin_amdgcn_mfma_f32_16x16x32_bf16(al, bh, acc1[ct], 0, 0, 0);
    }
  }

  // ======= GEMM1 part B: kq 128..351, register-direct A, NO barriers =======
  {
    const int r0c = w * 16 + lrow;       // 0..63
    const int nn = r0c & 3;
    const int dd = r0c >> 2;             // block-local d, 0..15
    const float* pv0 = sPv[nn + 1][dd];
    const unsigned short* enc = sEnc2[nn];
    const float m0 = (lg & 1) ? 256.f : 1.f;
    const bool usn = (lg < 2);

    auto mfmaB = [&](int kc, bf16x8 A0) {
      const bf16x8* wk = wfrag + (kc * 8) * 64 + lane;
      #pragma unroll
      for (int ct = 0; ct < 8; ++ct) {
        bf16x8 bh = wk[ct * 64];
        bf16x8 bl = wk[WT1 + ct * 64];
        acc1[ct] = __builtin_amdgcn_mfma_f32_16x16x32_bf16(A0, bh, acc1[ct], 0, 0, 0);
        acc1[ct] = __builtin_amdgcn_mfma_f32_16x16x32_bf16(A0, bl, acc1[ct], 0, 0, 0);
      }
    };
    // trig frag: element j has idx2 = lg*8+j in [0,32): scale 2^((lg&1)*8+j)
    auto trigf = [&](const float* pv, int comp) -> bf16x8 {
      float pA = pv[comp] * m0;
      unsigned ph[4];
      #pragma unroll
      for (int mj = 0; mj < 4; ++mj) {
        float a0f = pA * (float)(1 << (2 * mj));
        float a1f = pA * (float)(1 << (2 * mj + 1));
        float v0 = usn ? __sinf(a0f) : __cosf(a0f);
        float v1 = usn ? __sinf(a1f) : __cosf(a1f);
        ph[mj] = pk2bf(v0, v1);
      }
      union { unsigned u[4]; bf16x8 f; } cv;
      cv.u[0] = ph[0]; cv.u[1] = ph[1]; cv.u[2] = ph[2]; cv.u[3] = ph[3];
      return cv.f;
    };
    auto encf = [&](int off) -> bf16x8 {
      return *(const bf16x8*)&enc[off + lg * 8];
    };

    mfmaB(4, trigf(pv0, 0));
    mfmaB(5, trigf(pv0, 1));
    mfmaB(6, trigf(pv0, 2));
    {
      bf16x8 e0 = encf(0);
      if (lg == 0) {   // kq 224..226: raw xyz_iv (d-dependent)
        e0[0] = (short)f2b(pv0[0]); e0[1] = (short)f2b(pv0[1]); e0[2] = (short)f2b(pv0[2]);
      }
      mfmaB(7, e0);
    }
    mfmaB(8, encf(32));
    mfmaB(9, encf(64));
    mfmaB(10, encf(96));
  }
  __syncthreads();   // B6: sAw visible; all sFc reads done

  // ======= thread-local blend: hb[ld][c] = sum_i aw[i][ld]*silu(acc[i]) =======
  // acc1[ct][i]: row = w*16 + lg*4 + i -> ld = w*4 + lg, view = i.
  {
    int ld = w * 4 + lg;
    float a0 = sAw[0][ld], a1 = sAw[1][ld], a2 = sAw[2][ld], a3 = sAw[3][ld];
    #pragma unroll
    for (int ct = 0; ct < 8; ++ct) {
      int c = ct * 16 + lrow;
      float x0 = acc1[ct][0] + bias1[ct];
      float x1 = acc1[ct][1] + bias1[ct];
      float x2 = acc1[ct][2] + bias1[ct];
      float x3 = acc1[ct][3] + bias1[ct];
      float hb = a0 * __fdividef(x0, 1.f + __expf(-x0))
               + a1 * __fdividef(x1, 1.f + __expf(-x1))
               + a2 * __fdividef(x2, 1.f + __expf(-x2))
               + a3 * __fdividef(x3, 1.f + __expf(-x3));
      unsigned short hh = f2b(hb);
      unsigned short hl = f2b(hb - b2f(hh));
      int idx = (ld * 128 + c) ^ ((ld & 7) << 3);
      sHbHi[idx] = hh; sHbLo[idx] = hl;
    }
  }
  __syncthreads();   // B7

  // ======= GEMM2: fused = hb @ W2 + b2  (M=16, N=128) =======
  // wave w: col-tiles w*2, w*2+1.
  float bias2[2], wdv[2];
  #pragma unroll
  for (int cti = 0; cti < 2; ++cti) {
    int c = w * 32 + cti * 16 + lrow;
    bias2[cti] = b2p[c]; wdv[cti] = Wdp[c];
  }
  f32x4 acc2[2];
  acc2[0] = (f32x4){0.f, 0.f, 0.f, 0.f};
  acc2[1] = (f32x4){0.f, 0.f, 0.f, 0.f};
  {
    const int ar = lrow;
    #pragma unroll
    for (int kc = 0; kc < 4; ++kc) {
      int aidx = (ar * 128 + kc * 32 + 8 * lg) ^ ((ar & 7) << 3);
      bf16x8 ah = *(const bf16x8*)&sHbHi[aidx];
      bf16x8 al = *(const bf16x8*)&sHbLo[aidx];
      const bf16x8* wk = wfrag + 2 * WT1 + (kc * 8 + w * 2) * 64 + lane;
      #pragma unroll
      for (int cti = 0; cti < 2; ++cti) {
        bf16x8 bh = wk[cti * 64];
        bf16x8 bl = wk[WT2 + cti * 64];
        acc2[cti] = __builtin_amdgcn_mfma_f32_16x16x32_bf16(ah, bh, acc2[cti], 0, 0, 0);
        acc2[cti] = __builtin_amdgcn_mfma_f32_16x16x32_bf16(ah, bl, acc2[cti], 0, 0, 0);
        acc2[cti] = __builtin_amdgcn_mfma_f32_16x16x32_bf16(al, bh, acc2[cti], 0, 0, 0);
      }
    }
  }

  // ======= epilogue: stage fused (+out col) in LDS, then full-line writes =======
  {
    float part[4] = {0.f, 0.f, 0.f, 0.f};
    #pragma unroll
    for (int cti = 0; cti < 2; ++cti) {
      int c = w * 32 + cti * 16 + lrow;
      #pragma unroll
      for (int i = 0; i < 4; ++i) {
        int ld = lg * 4 + i;
        float fv = acc2[cti][i] + bias2[cti];
        sOut[ld * 129 + c] = fv;
        part[i] += fv * wdv[cti];
      }
    }
    #pragma unroll
    for (int i = 0; i < 4; ++i) {
      float p = part[i];
      #pragma unroll
      for (int o = 1; o < 16; o <<= 1) p += __shfl_xor(p, o);
      if (lrow == 0) sOutPart[w][lg * 4 + i] = p;
    }
  }
  __syncthreads();   // B8
  if (tid < 16)
    sOut[tid * 129 + 128] =
      sOutPart[0][tid] + sOutPart[1][tid] + sOutPart[2][tid] + sOutPart[3][tid];
  __syncthreads();   // B9
  {
    // per-block out0 slice is contiguous: 16*129*4 = 8256 B = 129 full lines,
    // (h*2+q)*8256 is 64B-aligned -> zero partial-line RMW.
    const float4* src = (const float4*)sOut;
    float4* dst = (float4*)(out0 + (size_t)h * (XD * 129) + (size_t)q * (16 * 129));
    for (int i = tid; i < (16 * 129) / 4; i += 256) dst[i] = src[i];
  }
}

extern "C" void kernel_launch(void* const* d_in, const int* in_sizes, int n_in,
                              void* d_out, int out_size, void* d_ws, size_t ws_size,
                              hipStream_t stream) {
  const float* xref = (const float*)d_in[0];
  const float* mask = (const float*)d_in[1];
  const float* rpts = (const float*)d_in[2];
  const float* rays = (const float*)d_in[3];
  const float* Rm   = (const float*)d_in[4];
  const float* Tm   = (const float*)d_in[5];
  const float* foc  = (const float*)d_in[6];
  const float* W1   = (const float*)d_in[7];
  const float* b1   = (const float*)d_in[8];
  const float* W2   = (const float*)d_in[9];
  const float* b2   = (const float*)d_in[10];
  const float* Wv   = (const float*)d_in[11];
  const float* bv   = (const float*)d_in[12];
  const float* Wd   = (const float*)d_in[13];
  float* out0 = (float*)d_out;
  float* out1 = out0 + (size_t)XH * XD * 129;

  hipLaunchKernelGGL(prep_frags, dim3(32), dim3(256), 0, stream,
                     W1, W2, (unsigned int*)d_ws);
  hipLaunchKernelGGL(nerf_main, dim3(XH * 2), dim3(256), 0, stream,
                     xref, mask, rpts, rays, Rm, Tm, foc,
                     b1, b2, Wv, bv, Wd, (const bf16x8*)d_ws, out0, out1);
}

// Round 6
// 68.662 us; speedup vs baseline: 1.1865x; 1.1865x over previous
//
#include <hip/hip_runtime.h>
#include <hip/hip_bf16.h>
#include <math.h>

// Shapes (fixed): B=1, N=4 views (V=5 incl. target), HW=1024, D=32, C=128,
// IN_DIM = 326, NUM_FREQS = 16, RES = 32.
#define XH 1024
#define XD 32
#define XC 128
#define XK 326

typedef __attribute__((ext_vector_type(8))) short bf16x8;
typedef __attribute__((ext_vector_type(4))) float f32x4;

__device__ __forceinline__ unsigned short f2b(float f) {
  unsigned u = __float_as_uint(f);
  return (unsigned short)((u + 0x7FFFu + ((u >> 16) & 1u)) >> 16);
}
__device__ __forceinline__ float b2f(unsigned short b) {
  return __uint_as_float(((unsigned)b) << 16);
}
__device__ __forceinline__ unsigned pk2bf(float v0, float v1) {
  __hip_bfloat162 h = __float22bfloat162_rn(make_float2(v0, v1));  // v_cvt_pk_bf16_f32
  return *reinterpret_cast<unsigned*>(&h);
}

// ws fragment tables (bf16 hi/lo split, B-operand lane layout for
// mfma_f32_16x16x32_bf16). frag element: lane l, j: B[k][c],
// k = kc*32 + 8*(l>>4) + j, c = ct*16 + (l&15).
// W1 padded K 326 -> 384 (12 kc); W2 K=128 (4 kc).
#define WT1 (12 * 8 * 64)   // 6144 fraglanes
#define WT2 (4 * 8 * 64)    // 2048 fraglanes

__global__ void prep_frags(const float* __restrict__ W1,
                           const float* __restrict__ W2,
                           unsigned int* __restrict__ ws) {
  int f = blockIdx.x * 256 + threadIdx.x;   // 0..8191
  if (f >= WT1 + WT2) return;
  const float* W; int KMAX; int fl; size_t hoff, loff;
  if (f < WT1) { W = W1; KMAX = XK; fl = f; hoff = 0; loff = WT1; }
  else { W = W2; KMAX = XC; fl = f - WT1; hoff = 2 * (size_t)WT1; loff = 2 * (size_t)WT1 + WT2; }
  int l = fl & 63, ct = (fl >> 6) & 7, kc = fl >> 9;
  int c = ct * 16 + (l & 15);
  int kbase = kc * 32 + 8 * (l >> 4);
  unsigned hi[4], lo[4];
  #pragma unroll
  for (int jj = 0; jj < 4; ++jj) {
    int k0 = kbase + 2 * jj;
    float w0 = (k0     < KMAX) ? W[k0 * XC + c]       : 0.f;
    float w1 = (k0 + 1 < KMAX) ? W[(k0 + 1) * XC + c] : 0.f;
    unsigned short h0 = f2b(w0); unsigned short l0 = f2b(w0 - b2f(h0));
    unsigned short h1 = f2b(w1); unsigned short l1 = f2b(w1 - b2f(h1));
    hi[jj] = (unsigned)h0 | ((unsigned)h1 << 16);
    lo[jj] = (unsigned)l0 | ((unsigned)l1 << 16);
  }
  uint4 vh; vh.x = hi[0]; vh.y = hi[1]; vh.z = hi[2]; vh.w = hi[3];
  uint4 vl; vl.x = lo[0]; vl.y = lo[1]; vl.z = lo[2]; vl.w = lo[3];
  *(uint4*)(ws + (hoff + fl) * 4) = vh;
  *(uint4*)(ws + (loff + fl) * 4) = vl;
}

// LDS layout (uMem = 64 KB):
//   sFcHi [128][128] bf16 at uMem+0      (GEMM1 A hi, kq 0..127)
//   sFcLo [128][128] bf16 at uMem+32768
//   hb hi [32][128] + lo [32][128] reuse uMem+32768 after GEMM1.
//   sOut  [32][129] f32 reuses uMem+0 after GEMM1.
//   swizzle (ushort idx): i ^ ((row&7)<<3)
// GEMM1 row order: lds_row = d*4 + n.
// kq 128..351 never touch sFc: A-fragments synthesized in registers (trig) or
// read from the per-n sEnc2 table. kc=11 all-zero -> skipped.
// Merged phase after B3: gather loads issued FIRST (8 float4 prefetched),
// sEnc2/sBt trig runs under the load latency, then blend/pack. One barrier
// fewer than round 4; all values byte-identical.

__global__ __launch_bounds__(512, 4)   // 4 waves/EU: 128-reg budget, NO spill
void nerf_main(const float* __restrict__ xref,   // (4,1024,128)
               const float* __restrict__ mask,   // (4,1024)
               const float* __restrict__ rpts,   // (1024,32,3)
               const float* __restrict__ rays,   // (5,1024,6)
               const float* __restrict__ Rm,     // (5,3,3)
               const float* __restrict__ Tm,     // (5,3)
               const float* __restrict__ focp,   // (5)
               const float* __restrict__ b1p,    // (128)
               const float* __restrict__ b2p,    // (128)
               const float* __restrict__ Wvp,    // (326)
               const float* __restrict__ bvp,    // (1)
               const float* __restrict__ Wdp,    // (128)
               const bf16x8* __restrict__ wfrag, // ws fragment tables
               float* __restrict__ out0,         // (1024,32,129)
               float* __restrict__ out1)         // (4,1024,32)
{
  const int h = blockIdx.x;
  const int tid = threadIdx.x;

  __shared__ float sR[5][3][3];
  __shared__ float sT[5][3];
  __shared__ float sFoc[5];
  __shared__ float sRay[5][6];
  __shared__ float sOiv[5][3];
  __shared__ float sDiv[5][3];
  __shared__ float sPlk[4][6];
  __shared__ float sOtg[4][3];
  __shared__ float sPv[5][32][3];
  __shared__ float sBc[4][32][4];
  __shared__ int   sBp[4][32][4];
  __shared__ float sWv[XK];
  __shared__ float sAt[32];
  __shared__ float sBt[4];
  __shared__ float sLogit[4][32];
  __shared__ float sAw[4][32];
  __shared__ float sOutPart[4][32];
  // per-n feature table for kq in [224,352): [pv_raw(3, zero here; patched
  // per-d at use), cam_iv_enc(96), d_iv(3), zero-pad(26)]  — bf16
  __shared__ __align__(16) unsigned short sEnc2[4][128];
  __shared__ __align__(16) unsigned char uMem[65536];
  unsigned short* sFcHi = (unsigned short*)uMem;             // [128*128]
  unsigned short* sFcLo = (unsigned short*)(uMem + 32768);   // [128*128]
  unsigned short* sHbHi = (unsigned short*)(uMem + 32768);   // [32*128]
  unsigned short* sHbLo = sHbHi + 32 * 128;                  // [32*128]
  float*          sOut  = (float*)uMem;                      // [32*129]

  // ---- stage small tensors ----
  for (int i = tid; i < 45; i += 512) ((float*)sR)[i] = Rm[i];
  for (int i = tid; i < 15; i += 512) ((float*)sT)[i] = Tm[i];
  for (int i = tid; i < 5;  i += 512) sFoc[i] = focp[i];
  for (int i = tid; i < 30; i += 512) { int v = i / 6, j = i % 6; sRay[v][j] = rays[(v*XH + h)*6 + j]; }
  for (int i = tid; i < XK; i += 512) sWv[i] = Wvp[i];
  __syncthreads();   // B1

  // ---- p_view + o_iv/d_iv ----
  if (tid < 160) {
    int v = tid >> 5, d = tid & 31;
    float p0 = rpts[(h*XD + d)*3 + 0];
    float p1 = rpts[(h*XD + d)*3 + 1];
    float p2 = rpts[(h*XD + d)*3 + 2];
    #pragma unroll
    for (int j = 0; j < 3; ++j)
      sPv[v][d][j] = p0*sR[v][0][j] + p1*sR[v][1][j] + p2*sR[v][2][j] + sT[v][j];
  } else if (tid < 165) {
    int v = tid - 160;
    #pragma unroll
    for (int j = 0; j < 3; ++j) {
      sOiv[v][j] = sRay[0][0]*sR[v][0][j] + sRay[0][1]*sR[v][1][j] + sRay[0][2]*sR[v][2][j] + sT[v][j];
      sDiv[v][j] = sRay[0][3]*sR[v][0][j] + sRay[0][4]*sR[v][1][j] + sRay[0][5]*sR[v][2][j];
    }
  }
  __syncthreads();   // B2

  // ---- plucker + o_tg + bilinear coefs  (+ sAt on threads 256..511) ----
  if (tid < 4) {
    int n = tid;
    float d0 = sDiv[n+1][0], d1 = sDiv[n+1][1], d2 = sDiv[n+1][2];
    float inv = 1.f / (sqrtf(d0*d0 + d1*d1 + d2*d2) + 1e-8f);
    float n0 = d0*inv, n1 = d1*inv, n2 = d2*inv;
    float o0 = sOiv[n+1][0], o1 = sOiv[n+1][1], o2 = sOiv[n+1][2];
    sPlk[n][0] = n0; sPlk[n][1] = n1; sPlk[n][2] = n2;
    sPlk[n][3] = o1*n2 - o2*n1;
    sPlk[n][4] = o2*n0 - o0*n2;
    sPlk[n][5] = o0*n1 - o1*n0;
    #pragma unroll
    for (int j = 0; j < 3; ++j)
      sOtg[n][j] = sRay[1+n][0]*sR[0][0][j] + sRay[1+n][1]*sR[0][1][j] + sRay[1+n][2]*sR[0][2][j] + sT[0][j];
  }
  if (tid >= 32 && tid < 160) {
    int idx = tid - 32, n = idx >> 5, d = idx & 31, v = n + 1;
    float px = sPv[v][d][0], py = sPv[v][d][1], pz = sPv[v][d][2], fo = sFoc[v];
    float gx = -(fo*px)/pz, gy = -(fo*py)/pz;
    if (isnan(gx)) gx = 0.f;
    if (isnan(gy)) gy = 0.f;
    gx = fminf(fmaxf(gx, -1.2f), 1.2f);
    gy = fminf(fmaxf(gy, -1.2f), 1.2f);
    float x = (gx + 1.f)*15.5f, y = (gy + 1.f)*15.5f;
    float x0f = floorf(x), y0f = floorf(y);
    float wx1 = x - x0f, wx0 = 1.f - wx1;
    float wy1 = y - y0f, wy0 = 1.f - wy1;
    int x0i = (int)x0f, y0i = (int)y0f;
    bool vx0 = (x0f >=  0.f) & (x0f <= 31.f);
    bool vx1 = (x0f >= -1.f) & (x0f <= 30.f);
    bool vy0 = (y0f >=  0.f) & (y0f <= 31.f);
    bool vy1 = (y0f >= -1.f) & (y0f <= 30.f);
    int x0c = min(max(x0i, 0), 31), x1c = min(max(x0i + 1, 0), 31);
    int y0c = min(max(y0i, 0), 31), y1c = min(max(y0i + 1, 0), 31);
    int p00 = y0c*32 + x0c, p10 = y0c*32 + x1c, p01 = y1c*32 + x0c, p11 = y1c*32 + x1c;
    sBc[n][d][0] = wx0*wy0*((vx0 && vy0) ? mask[n*XH + p00] : 0.f);
    sBc[n][d][1] = wx1*wy0*((vx1 && vy0) ? mask[n*XH + p10] : 0.f);
    sBc[n][d][2] = wx0*wy1*((vx0 && vy1) ? mask[n*XH + p01] : 0.f);
    sBc[n][d][3] = wx1*wy1*((vx1 && vy1) ? mask[n*XH + p11] : 0.f);
    sBp[n][d][0] = p00; sBp[n][d][1] = p10; sBp[n][d][2] = p01; sBp[n][d][3] = p11;
  }
  if (tid >= 256) {
    // sAt: xyz_iv_enc[view 0] . Wv slice (needs only sPv[0], sWv)
    int t = tid - 256;
    int d = t >> 3, sub = t & 7;
    float p = 0.f;
    for (int kk = sub * 12; kk < sub * 12 + 12; ++kk) {
      int comp = kk >> 5, idx = kk & 31;
      float ang = sPv[0][d][comp] * (float)(1 << (idx & 15));
      float ev = (idx < 16) ? __sinf(ang) : __cosf(ang);
      p += ev * sWv[128 + kk];
    }
    if (sub == 0)
      for (int j = 0; j < 3; ++j) p += sPv[0][d][j] * sWv[224 + j];
    #pragma unroll
    for (int o = 1; o < 8; o <<= 1) p += __shfl_xor(p, o);
    if (sub == 0) sAt[d] = p;
  }
  __syncthreads();   // B3

  // build-thread constants: lds row = d*4 + n
  const int brow = tid >> 2;            // 0..127
  const int bn = brow & 3, bd = brow >> 2;
  const int kloc0 = (tid & 3) * 16;     // k offset within row
  float plog = 0.f;                     // logit partial (kq 0..127)

  // ======= MERGED phase: gather (loads first) + sEnc2/sBt trig + pack =======
  {
    const float* bc = sBc[bn][bd];
    const int*   bp = sBp[bn][bd];
    const float* xb = xref + bn * XH * XC;

    // -- issue chunk-0 q=0,1 loads early (latency hides under trig below) --
    float4 pf[8];
    #pragma unroll
    for (int qq = 0; qq < 2; ++qq) {
      pf[qq*4+0] = *(const float4*)(xb + bp[0] * XC + kloc0 + 4 * qq);
      pf[qq*4+1] = *(const float4*)(xb + bp[1] * XC + kloc0 + 4 * qq);
      pf[qq*4+2] = *(const float4*)(xb + bp[2] * XC + kloc0 + 4 * qq);
      pf[qq*4+3] = *(const float4*)(xb + bp[3] * XC + kloc0 + 4 * qq);
    }

    // -- sEnc2 fill (all 512 threads; deps sPlk/sDiv ready at B3) --
    {
      int n = tid >> 7, off = tid & 127;
      float val = 0.f;
      if (off >= 3 && off < 99) {
        int kk = off - 3;                       // cam_iv_enc index
        int comp = kk >> 4, idx = kk & 15;
        float ang = sPlk[n][comp] * (float)(1 << (idx & 7));
        val = (idx < 8) ? __sinf(ang) : __cosf(ang);
      } else if (off >= 99 && off < 102) {
        val = sDiv[n + 1][off - 99];
      }
      sEnc2[n][off] = f2b(val);
    }
    // -- sBt (threads 256..287; deps sOtg ready at B3) --
    if (tid >= 256 && tid < 288) {
      int t = tid - 256, n = t >> 3, sub = t & 7;
      float p = 0.f;
      for (int kk = sub * 12; kk < sub * 12 + 12; ++kk) {
        int comp = kk >> 5, idx = kk & 31;
        float ang = sOtg[n][comp] * (float)(1 << (idx & 15));
        float ev = (idx < 16) ? __sinf(ang) : __cosf(ang);
        p += ev * sWv[230 + kk];
      }
      if (sub == 0) {
        for (int j = 0; j < 3; ++j) p += sOtg[n][j] * sWv[227 + j];
        p += bvp[0];
      }
      #pragma unroll
      for (int o = 1; o < 8; o <<= 1) p += __shfl_xor(p, o);
      if (sub == 0) sBt[n] = p;
    }

    // -- chunk 0 blend/pack (q<2 from prefetch regs) --
    {
      int kg = kloc0;
      float vv[16];
      #pragma unroll
      for (int qq = 0; qq < 4; ++qq) {
        float4 a0, a1, a2, a3;
        if (qq < 2) {
          a0 = pf[qq*4+0]; a1 = pf[qq*4+1]; a2 = pf[qq*4+2]; a3 = pf[qq*4+3];
        } else {
          a0 = *(const float4*)(xb + bp[0] * XC + kg + 4 * qq);
          a1 = *(const float4*)(xb + bp[1] * XC + kg + 4 * qq);
          a2 = *(const float4*)(xb + bp[2] * XC + kg + 4 * qq);
          a3 = *(const float4*)(xb + bp[3] * XC + kg + 4 * qq);
        }
        #pragma unroll
        for (int j = 0; j < 4; ++j)
          vv[4 * qq + j] = bc[0]*(&a0.x)[j] + bc[1]*(&a1.x)[j]
                         + bc[2]*(&a2.x)[j] + bc[3]*(&a3.x)[j];
      }
      #pragma unroll
      for (int j = 0; j < 16; ++j) plog += vv[j] * sWv[kg + j];
      #pragma unroll
      for (int qq = 0; qq < 2; ++qq) {
        unsigned ph[4], pl[4];
        #pragma unroll
        for (int j = 0; j < 4; ++j) {
          float v0 = vv[8 * qq + 2 * j], v1 = vv[8 * qq + 2 * j + 1];
          unsigned hp = pk2bf(v0, v1);
          float r0 = v0 - b2f((unsigned short)(hp & 0xFFFF));
          float r1 = v1 - b2f((unsigned short)(hp >> 16));
          ph[j] = hp;
          pl[j] = pk2bf(r0, r1);
        }
        int gidx = (brow * 128 + kg + 8 * qq) ^ ((brow & 7) << 3);
        *(uint4*)&sFcHi[gidx] = *(uint4*)ph;
        *(uint4*)&sFcLo[gidx] = *(uint4*)pl;
      }
    }
    // -- chunk 1 (loads + blend/pack) --
    {
      int kg = 64 + kloc0;
      float vv[16];
      #pragma unroll
      for (int qq = 0; qq < 4; ++qq) {
        float4 a0 = *(const float4*)(xb + bp[0] * XC + kg + 4 * qq);
        float4 a1 = *(const float4*)(xb + bp[1] * XC + kg + 4 * qq);
        float4 a2 = *(const float4*)(xb + bp[2] * XC + kg + 4 * qq);
        float4 a3 = *(const float4*)(xb + bp[3] * XC + kg + 4 * qq);
        #pragma unroll
        for (int j = 0; j < 4; ++j)
          vv[4 * qq + j] = bc[0]*(&a0.x)[j] + bc[1]*(&a1.x)[j]
                         + bc[2]*(&a2.x)[j] + bc[3]*(&a3.x)[j];
      }
      #pragma unroll
      for (int j = 0; j < 16; ++j) plog += vv[j] * sWv[kg + j];
      #pragma unroll
      for (int qq = 0; qq < 2; ++qq) {
        unsigned ph[4], pl[4];
        #pragma unroll
        for (int j = 0; j < 4; ++j) {
          float v0 = vv[8 * qq + 2 * j], v1 = vv[8 * qq + 2 * j + 1];
          unsigned hp = pk2bf(v0, v1);
          float r0 = v0 - b2f((unsigned short)(hp & 0xFFFF));
          float r1 = v1 - b2f((unsigned short)(hp >> 16));
          ph[j] = hp;
          pl[j] = pk2bf(r0, r1);
        }
        int gidx = (brow * 128 + kg + 8 * qq) ^ ((brow & 7) << 3);
        *(uint4*)&sFcHi[gidx] = *(uint4*)ph;
        *(uint4*)&sFcLo[gidx] = *(uint4*)pl;
      }
    }
    // logit partial reduce (4 threads per (n,d))
    {
      float p = plog;
      p += __shfl_xor(p, 1);
      p += __shfl_xor(p, 2);
      if ((tid & 3) == 0) sLogit[bn][bd] = p;
    }
  }
  __syncthreads();   // B4: sFc + sLogit + sEnc2 + sBt ready

  // ---- softmax over n (wave 0 lanes 0..31; runs while others MFMA) ----
  if (tid < 32) {
    int d = tid;
    float l0 = sLogit[0][d] + sAt[d] + sBt[0];
    float l1 = sLogit[1][d] + sAt[d] + sBt[1];
    float l2 = sLogit[2][d] + sAt[d] + sBt[2];
    float l3 = sLogit[3][d] + sAt[d] + sBt[3];
    float m = fmaxf(fmaxf(l0, l1), fmaxf(l2, l3));
    float e0 = __expf(l0 - m), e1 = __expf(l1 - m), e2 = __expf(l2 - m), e3 = __expf(l3 - m);
    float inv = 1.f / (e0 + e1 + e2 + e3);
    float w0 = e0*inv, w1 = e1*inv, w2 = e2*inv, w3 = e3*inv;
    sAw[0][d] = w0; sAw[1][d] = w1; sAw[2][d] = w2; sAw[3][d] = w3;
    out1[(0*XH + h)*XD + d] = w0;
    out1[(1*XH + h)*XD + d] = w1;
    out1[(2*XH + h)*XD + d] = w2;
    out1[(3*XH + h)*XD + d] = w3;
  }

  // ---- wave decomposition for GEMM1: M=128 rows (row = d*4 + n) ----
  const int w = tid >> 6, lane = tid & 63;
  const int rt = w & 3, cg = w >> 2;
  const int lrow = lane & 15, lg = lane >> 4;
  float bias1[4];
  #pragma unroll
  for (int ct = 0; ct < 4; ++ct) bias1[ct] = b1p[cg * 64 + ct * 16 + lrow];

  f32x4 acc1[2][4];
  #pragma unroll
  for (int rf = 0; rf < 2; ++rf)
    #pragma unroll
    for (int ct = 0; ct < 4; ++ct) acc1[rf][ct] = (f32x4){0.f, 0.f, 0.f, 0.f};

  // ======= GEMM1 part A: kq 0..127 from LDS (4 kc, one contiguous run) =======
  #pragma unroll
  for (int sk = 0; sk < 4; ++sk) {
    const int r0 = rt * 32 + lrow;
    const int ai0 = (r0 * 128 + sk * 32 + 8 * lg) ^ ((r0 & 7) << 3);
    const int ai1 = ai0 + 16 * 128;   // r1 = r0+16: same (r&7) swizzle
    bf16x8 ah0 = *(const bf16x8*)&sFcHi[ai0];
    bf16x8 ah1 = *(const bf16x8*)&sFcHi[ai1];
    bf16x8 al0 = *(const bf16x8*)&sFcLo[ai0];
    bf16x8 al1 = *(const bf16x8*)&sFcLo[ai1];
    const bf16x8* wkh = wfrag + (sk * 8 + cg * 4) * 64 + lane;  // per-kc base
    const bf16x8* wkl = wkh + WT1;
    #pragma unroll
    for (int ct = 0; ct < 4; ++ct) {
      bf16x8 bh = wkh[ct * 64];   // offset: ct*1024 B — immediate
      bf16x8 bl = wkl[ct * 64];
      acc1[0][ct] = __builtin_amdgcn_mfma_f32_16x16x32_bf16(ah0, bh, acc1[0][ct], 0, 0, 0);
      acc1[0][ct] = __builtin_amdgcn_mfma_f32_16x16x32_bf16(ah0, bl, acc1[0][ct], 0, 0, 0);
      acc1[0][ct] = __builtin_amdgcn_mfma_f32_16x16x32_bf16(al0, bh, acc1[0][ct], 0, 0, 0);
      acc1[1][ct] = __builtin_amdgcn_mfma_f32_16x16x32_bf16(ah1, bh, acc1[1][ct], 0, 0, 0);
      acc1[1][ct] = __builtin_amdgcn_mfma_f32_16x16x32_bf16(ah1, bl, acc1[1][ct], 0, 0, 0);
      acc1[1][ct] = __builtin_amdgcn_mfma_f32_16x16x32_bf16(al1, bh, acc1[1][ct], 0, 0, 0);
    }
  }

  // ======= GEMM1 part B: kq 128..351, register-direct A, NO barriers =======
  {
    const int r0c = rt * 32 + lrow;
    const int nn = r0c & 3;              // same n for both rows
    const int dd = r0c >> 2;             // row1 has d = dd+4
    const float* pv0 = sPv[nn + 1][dd];
    const float* pv1 = sPv[nn + 1][dd + 4];
    const unsigned short* enc = sEnc2[nn];
    const float m0 = (lg & 1) ? 256.f : 1.f;
    const bool usn = (lg < 2);

    auto mfma4 = [&](int kc, bf16x8 A0, bf16x8 A1) {
      const bf16x8* wkh = wfrag + (kc * 8 + cg * 4) * 64 + lane;
      const bf16x8* wkl = wkh + WT1;
      #pragma unroll
      for (int ct = 0; ct < 4; ++ct) {
        bf16x8 bh = wkh[ct * 64];
        bf16x8 bl = wkl[ct * 64];
        acc1[0][ct] = __builtin_amdgcn_mfma_f32_16x16x32_bf16(A0, bh, acc1[0][ct], 0, 0, 0);
        acc1[0][ct] = __builtin_amdgcn_mfma_f32_16x16x32_bf16(A0, bl, acc1[0][ct], 0, 0, 0);
        acc1[1][ct] = __builtin_amdgcn_mfma_f32_16x16x32_bf16(A1, bh, acc1[1][ct], 0, 0, 0);
        acc1[1][ct] = __builtin_amdgcn_mfma_f32_16x16x32_bf16(A1, bl, acc1[1][ct], 0, 0, 0);
      }
    };
    // trig frag: element j has idx2 = lg*8+j in [0,32): scale 2^((lg&1)*8+j)
    auto trigf = [&](const float* pv, int comp) -> bf16x8 {
      float pA = pv[comp] * m0;
      unsigned ph[4];
      #pragma unroll
      for (int mj = 0; mj < 4; ++mj) {
        float a0f = pA * (float)(1 << (2 * mj));
        float a1f = pA * (float)(1 << (2 * mj + 1));
        float v0 = usn ? __sinf(a0f) : __cosf(a0f);
        float v1 = usn ? __sinf(a1f) : __cosf(a1f);
        ph[mj] = pk2bf(v0, v1);
      }
      union { unsigned u[4]; bf16x8 f; } cv;
      cv.u[0] = ph[0]; cv.u[1] = ph[1]; cv.u[2] = ph[2]; cv.u[3] = ph[3];
      return cv.f;
    };
    auto encf = [&](int off) -> bf16x8 {
      return *(const bf16x8*)&enc[off + lg * 8];
    };

    mfma4(4, trigf(pv0, 0), trigf(pv1, 0));
    mfma4(5, trigf(pv0, 1), trigf(pv1, 1));
    mfma4(6, trigf(pv0, 2), trigf(pv1, 2));
    {
      bf16x8 e0 = encf(0);
      bf16x8 e1 = e0;
      if (lg == 0) {   // kq 224..226: raw xyz_iv (d-dependent)
        e0[0] = (short)f2b(pv0[0]); e0[1] = (short)f2b(pv0[1]); e0[2] = (short)f2b(pv0[2]);
        e1[0] = (short)f2b(pv1[0]); e1[1] = (short)f2b(pv1[1]); e1[2] = (short)f2b(pv1[2]);
      }
      mfma4(7, e0, e1);
    }
    { bf16x8 e = encf(32); mfma4(8, e, e); }
    { bf16x8 e = encf(64); mfma4(9, e, e); }
    { bf16x8 e = encf(96); mfma4(10, e, e); }
  }
  __syncthreads();   // B5: sAw visible; all sFc reads done

  // ======= thread-local blend: hb[d][c] = sum_i aw[i][d]*silu(acc[i]) =======
  // acc1[rf][ct][i]: row = tile*16 + lg*4 + i -> d = (rt*2+rf)*4 + lg, view = i.
  #pragma unroll
  for (int rf = 0; rf < 2; ++rf) {
    int d = (rt * 2 + rf) * 4 + lg;
    float a0 = sAw[0][d], a1 = sAw[1][d], a2 = sAw[2][d], a3 = sAw[3][d];
    #pragma unroll
    for (int ct = 0; ct < 4; ++ct) {
      int c = cg * 64 + ct * 16 + lrow;
      float x0 = acc1[rf][ct][0] + bias1[ct];
      float x1 = acc1[rf][ct][1] + bias1[ct];
      float x2 = acc1[rf][ct][2] + bias1[ct];
      float x3 = acc1[rf][ct][3] + bias1[ct];
      float hb = a0 * __fdividef(x0, 1.f + __expf(-x0))
               + a1 * __fdividef(x1, 1.f + __expf(-x1))
               + a2 * __fdividef(x2, 1.f + __expf(-x2))
               + a3 * __fdividef(x3, 1.f + __expf(-x3));
      unsigned short hh = f2b(hb);
      unsigned short hl = f2b(hb - b2f(hh));
      int idx = (d * 128 + c) ^ ((d & 7) << 3);
      sHbHi[idx] = hh; sHbLo[idx] = hl;
    }
  }
  __syncthreads();   // B6

  // ======= GEMM2 (split): fused = hb @ W2 + b2  (M=32) =======
  const int rt2 = w & 1, cg2 = w >> 1;
  float bias2[2], wdv[2];
  #pragma unroll
  for (int cti = 0; cti < 2; ++cti) {
    int c = cg2 * 32 + cti * 16 + lrow;
    bias2[cti] = b2p[c]; wdv[cti] = Wdp[c];
  }
  f32x4 acc2[2];
  acc2[0] = (f32x4){0.f, 0.f, 0.f, 0.f};
  acc2[1] = (f32x4){0.f, 0.f, 0.f, 0.f};
  {
    const int ar = rt2 * 16 + lrow;
    #pragma unroll
    for (int kc = 0; kc < 4; ++kc) {
      int aidx = (ar * 128 + kc * 32 + 8 * lg) ^ ((ar & 7) << 3);
      bf16x8 ah = *(const bf16x8*)&sHbHi[aidx];
      bf16x8 al = *(const bf16x8*)&sHbLo[aidx];
      const bf16x8* wkh = wfrag + 2 * WT1 + (kc * 8 + cg2 * 2) * 64 + lane;
      const bf16x8* wkl = wkh + WT2;
      #pragma unroll
      for (int cti = 0; cti < 2; ++cti) {
        bf16x8 bh = wkh[cti * 64];
        bf16x8 bl = wkl[cti * 64];
        acc2[cti] = __builtin_amdgcn_mfma_f32_16x16x32_bf16(ah, bh, acc2[cti], 0, 0, 0);
        acc2[cti] = __builtin_amdgcn_mfma_f32_16x16x32_bf16(ah, bl, acc2[cti], 0, 0, 0);
        acc2[cti] = __builtin_amdgcn_mfma_f32_16x16x32_bf16(al, bh, acc2[cti], 0, 0, 0);
      }
    }
  }

  // ======= epilogue: stage fused (+out col) in LDS, then full-line writes =======
  {
    float part[4] = {0.f, 0.f, 0.f, 0.f};
    #pragma unroll
    for (int cti = 0; cti < 2; ++cti) {
      int c = cg2 * 32 + cti * 16 + lrow;
      #pragma unroll
      for (int i = 0; i < 4; ++i) {
        int d = rt2 * 16 + lg * 4 + i;
        float fv = acc2[cti][i] + bias2[cti];
        sOut[d * 129 + c] = fv;
        part[i] += fv * wdv[cti];
      }
    }
    #pragma unroll
    for (int i = 0; i < 4; ++i) {
      float p = part[i];
      #pragma unroll
      for (int o = 1; o < 16; o <<= 1) p += __shfl_xor(p, o);
      if (lrow == 0) sOutPart[cg2][rt2 * 16 + lg * 4 + i] = p;
    }
  }
  __syncthreads();   // B7
  if (tid < 32)
    sOut[tid * 129 + 128] =
      sOutPart[0][tid] + sOutPart[1][tid] + sOutPart[2][tid] + sOutPart[3][tid];
  __syncthreads();   // B8
  {
    // per-block out0 slice is contiguous: 32*129*4 = 16512 B = 258 full lines,
    // h*16512 is 64B-aligned -> zero partial-line RMW.
    const float4* src = (const float4*)sOut;
    float4* dst = (float4*)(out0 + (size_t)h * (XD * 129));
    for (int i = tid; i < (XD * 129) / 4; i += 512) dst[i] = src[i];
  }
}

extern "C" void kernel_launch(void* const* d_in, const int* in_sizes, int n_in,
                              void* d_out, int out_size, void* d_ws, size_t ws_size,
                              hipStream_t stream) {
  const float* xref = (const float*)d_in[0];
  const float* mask = (const float*)d_in[1];
  const float* rpts = (const float*)d_in[2];
  const float* rays = (const float*)d_in[3];
  const float* Rm   = (const float*)d_in[4];
  const float* Tm   = (const float*)d_in[5];
  const float* foc  = (const float*)d_in[6];
  const float* W1   = (const float*)d_in[7];
  const float* b1   = (const float*)d_in[8];
  const float* W2   = (const float*)d_in[9];
  const float* b2   = (const float*)d_in[10];
  const float* Wv   = (const float*)d_in[11];
  const float* bv   = (const float*)d_in[12];
  const float* Wd   = (const float*)d_in[13];
  float* out0 = (float*)d_out;
  float* out1 = out0 + (size_t)XH * XD * 129;

  hipLaunchKernelGGL(prep_frags, dim3(32), dim3(256), 0, stream,
                     W1, W2, (unsigned int*)d_ws);
  hipLaunchKernelGGL(nerf_main, dim3(XH), dim3(512), 0, stream,
                     xref, mask, rpts, rays, Rm, Tm, foc,
                     b1, b2, Wv, bv, Wd, (const bf16x8*)d_ws, out0, out1);
}

// Round 7
// 65.423 us; speedup vs baseline: 1.2453x; 1.0495x over previous
//
#include <hip/hip_runtime.h>
#include <hip/hip_bf16.h>
#include <math.h>

// Shapes (fixed): B=1, N=4 views (V=5 incl. target), HW=1024, D=32, C=128,
// IN_DIM = 326, NUM_FREQS = 16, RES = 32.
#define XH 1024
#define XD 32
#define XC 128
#define XK 326

typedef __attribute__((ext_vector_type(8))) short bf16x8;
typedef __attribute__((ext_vector_type(4))) float f32x4;

__device__ __forceinline__ unsigned short f2b(float f) {
  unsigned u = __float_as_uint(f);
  return (unsigned short)((u + 0x7FFFu + ((u >> 16) & 1u)) >> 16);
}
__device__ __forceinline__ float b2f(unsigned short b) {
  return __uint_as_float(((unsigned)b) << 16);
}
__device__ __forceinline__ unsigned pk2bf(float v0, float v1) {
  __hip_bfloat162 h = __float22bfloat162_rn(make_float2(v0, v1));  // v_cvt_pk_bf16_f32
  return *reinterpret_cast<unsigned*>(&h);
}

// ws fragment tables (bf16 hi/lo split, B-operand lane layout for
// mfma_f32_16x16x32_bf16). frag element: lane l, j: B[k][c],
// k = kc*32 + 8*(l>>4) + j, c = ct*16 + (l&15).
// W1 padded K 326 -> 384 (12 kc); W2 K=128 (4 kc).
#define WT1 (12 * 8 * 64)   // 6144 fraglanes
#define WT2 (4 * 8 * 64)    // 2048 fraglanes

__global__ void prep_frags(const float* __restrict__ W1,
                           const float* __restrict__ W2,
                           unsigned int* __restrict__ ws) {
  int f = blockIdx.x * 256 + threadIdx.x;   // 0..8191
  if (f >= WT1 + WT2) return;
  const float* W; int KMAX; int fl; size_t hoff, loff;
  if (f < WT1) { W = W1; KMAX = XK; fl = f; hoff = 0; loff = WT1; }
  else { W = W2; KMAX = XC; fl = f - WT1; hoff = 2 * (size_t)WT1; loff = 2 * (size_t)WT1 + WT2; }
  int l = fl & 63, ct = (fl >> 6) & 7, kc = fl >> 9;
  int c = ct * 16 + (l & 15);
  int kbase = kc * 32 + 8 * (l >> 4);
  unsigned hi[4], lo[4];
  #pragma unroll
  for (int jj = 0; jj < 4; ++jj) {
    int k0 = kbase + 2 * jj;
    float w0 = (k0     < KMAX) ? W[k0 * XC + c]       : 0.f;
    float w1 = (k0 + 1 < KMAX) ? W[(k0 + 1) * XC + c] : 0.f;
    unsigned short h0 = f2b(w0); unsigned short l0 = f2b(w0 - b2f(h0));
    unsigned short h1 = f2b(w1); unsigned short l1 = f2b(w1 - b2f(h1));
    hi[jj] = (unsigned)h0 | ((unsigned)h1 << 16);
    lo[jj] = (unsigned)l0 | ((unsigned)l1 << 16);
  }
  uint4 vh; vh.x = hi[0]; vh.y = hi[1]; vh.z = hi[2]; vh.w = hi[3];
  uint4 vl; vl.x = lo[0]; vl.y = lo[1]; vl.z = lo[2]; vl.w = lo[3];
  *(uint4*)(ws + (hoff + fl) * 4) = vh;
  *(uint4*)(ws + (loff + fl) * 4) = vl;
}

// LDS layout (uMem = 64 KB):
//   sFcHi [128][128] bf16 at uMem+0      (GEMM1 A hi, kq 0..127)
//   sFcLo [128][128] bf16 at uMem+32768
//   hb hi [32][128] + lo [32][128] reuse uMem+32768 after GEMM1.
//   sOut  [32][129] f32 reuses uMem+0 after GEMM1.
//   swizzle (ushort idx): i ^ ((row&7)<<3)
// GEMM1 row order: lds_row = d*4 + n.
// kq 128..351 never touch sFc: A-fragments synthesized in registers (trig) or
// read from the per-n sEnc2 table. kc=11 all-zero -> skipped.
// GEMM1 is ONE barrier-free region with part A (LDS) and part B (trig/enc)
// kc-steps INTERLEAVED: trig VALU covers wfrag L2 latency, MFMAs cover trig.

__global__ __launch_bounds__(512, 4)   // 4 waves/EU: 128-reg budget, NO spill
void nerf_main(const float* __restrict__ xref,   // (4,1024,128)
               const float* __restrict__ mask,   // (4,1024)
               const float* __restrict__ rpts,   // (1024,32,3)
               const float* __restrict__ rays,   // (5,1024,6)
               const float* __restrict__ Rm,     // (5,3,3)
               const float* __restrict__ Tm,     // (5,3)
               const float* __restrict__ focp,   // (5)
               const float* __restrict__ b1p,    // (128)
               const float* __restrict__ b2p,    // (128)
               const float* __restrict__ Wvp,    // (326)
               const float* __restrict__ bvp,    // (1)
               const float* __restrict__ Wdp,    // (128)
               const bf16x8* __restrict__ wfrag, // ws fragment tables
               float* __restrict__ out0,         // (1024,32,129)
               float* __restrict__ out1)         // (4,1024,32)
{
  const int h = blockIdx.x;
  const int tid = threadIdx.x;

  __shared__ float sR[5][3][3];
  __shared__ float sT[5][3];
  __shared__ float sFoc[5];
  __shared__ float sRay[5][6];
  __shared__ float sOiv[5][3];
  __shared__ float sDiv[5][3];
  __shared__ float sPlk[4][6];
  __shared__ float sOtg[4][3];
  __shared__ float sPv[5][32][3];
  __shared__ float sBc[4][32][4];
  __shared__ int   sBp[4][32][4];
  __shared__ float sWv[XK];
  __shared__ float sAt[32];
  __shared__ float sBt[4];
  __shared__ float sLogit[4][32];
  __shared__ float sAw[4][32];
  __shared__ float sOutPart[4][32];
  // per-n feature table for kq in [224,352): [pv_raw(3, zero here; patched
  // per-d at use), cam_iv_enc(96), d_iv(3), zero-pad(26)]  — bf16
  __shared__ __align__(16) unsigned short sEnc2[4][128];
  __shared__ __align__(16) unsigned char uMem[65536];
  unsigned short* sFcHi = (unsigned short*)uMem;             // [128*128]
  unsigned short* sFcLo = (unsigned short*)(uMem + 32768);   // [128*128]
  unsigned short* sHbHi = (unsigned short*)(uMem + 32768);   // [32*128]
  unsigned short* sHbLo = sHbHi + 32 * 128;                  // [32*128]
  float*          sOut  = (float*)uMem;                      // [32*129]

  // ---- stage small tensors ----
  for (int i = tid; i < 45; i += 512) ((float*)sR)[i] = Rm[i];
  for (int i = tid; i < 15; i += 512) ((float*)sT)[i] = Tm[i];
  for (int i = tid; i < 5;  i += 512) sFoc[i] = focp[i];
  for (int i = tid; i < 30; i += 512) { int v = i / 6, j = i % 6; sRay[v][j] = rays[(v*XH + h)*6 + j]; }
  for (int i = tid; i < XK; i += 512) sWv[i] = Wvp[i];
  __syncthreads();   // B1

  // ---- p_view + o_iv/d_iv ----
  if (tid < 160) {
    int v = tid >> 5, d = tid & 31;
    float p0 = rpts[(h*XD + d)*3 + 0];
    float p1 = rpts[(h*XD + d)*3 + 1];
    float p2 = rpts[(h*XD + d)*3 + 2];
    #pragma unroll
    for (int j = 0; j < 3; ++j)
      sPv[v][d][j] = p0*sR[v][0][j] + p1*sR[v][1][j] + p2*sR[v][2][j] + sT[v][j];
  } else if (tid < 165) {
    int v = tid - 160;
    #pragma unroll
    for (int j = 0; j < 3; ++j) {
      sOiv[v][j] = sRay[0][0]*sR[v][0][j] + sRay[0][1]*sR[v][1][j] + sRay[0][2]*sR[v][2][j] + sT[v][j];
      sDiv[v][j] = sRay[0][3]*sR[v][0][j] + sRay[0][4]*sR[v][1][j] + sRay[0][5]*sR[v][2][j];
    }
  }
  __syncthreads();   // B2

  // ---- plucker + o_tg + bilinear coefs  (+ sAt on threads 256..511) ----
  if (tid < 4) {
    int n = tid;
    float d0 = sDiv[n+1][0], d1 = sDiv[n+1][1], d2 = sDiv[n+1][2];
    float inv = 1.f / (sqrtf(d0*d0 + d1*d1 + d2*d2) + 1e-8f);
    float n0 = d0*inv, n1 = d1*inv, n2 = d2*inv;
    float o0 = sOiv[n+1][0], o1 = sOiv[n+1][1], o2 = sOiv[n+1][2];
    sPlk[n][0] = n0; sPlk[n][1] = n1; sPlk[n][2] = n2;
    sPlk[n][3] = o1*n2 - o2*n1;
    sPlk[n][4] = o2*n0 - o0*n2;
    sPlk[n][5] = o0*n1 - o1*n0;
    #pragma unroll
    for (int j = 0; j < 3; ++j)
      sOtg[n][j] = sRay[1+n][0]*sR[0][0][j] + sRay[1+n][1]*sR[0][1][j] + sRay[1+n][2]*sR[0][2][j] + sT[0][j];
  }
  if (tid >= 32 && tid < 160) {
    int idx = tid - 32, n = idx >> 5, d = idx & 31, v = n + 1;
    float px = sPv[v][d][0], py = sPv[v][d][1], pz = sPv[v][d][2], fo = sFoc[v];
    float gx = -(fo*px)/pz, gy = -(fo*py)/pz;
    if (isnan(gx)) gx = 0.f;
    if (isnan(gy)) gy = 0.f;
    gx = fminf(fmaxf(gx, -1.2f), 1.2f);
    gy = fminf(fmaxf(gy, -1.2f), 1.2f);
    float x = (gx + 1.f)*15.5f, y = (gy + 1.f)*15.5f;
    float x0f = floorf(x), y0f = floorf(y);
    float wx1 = x - x0f, wx0 = 1.f - wx1;
    float wy1 = y - y0f, wy0 = 1.f - wy1;
    int x0i = (int)x0f, y0i = (int)y0f;
    bool vx0 = (x0f >=  0.f) & (x0f <= 31.f);
    bool vx1 = (x0f >= -1.f) & (x0f <= 30.f);
    bool vy0 = (y0f >=  0.f) & (y0f <= 31.f);
    bool vy1 = (y0f >= -1.f) & (y0f <= 30.f);
    int x0c = min(max(x0i, 0), 31), x1c = min(max(x0i + 1, 0), 31);
    int y0c = min(max(y0i, 0), 31), y1c = min(max(y0i + 1, 0), 31);
    int p00 = y0c*32 + x0c, p10 = y0c*32 + x1c, p01 = y1c*32 + x0c, p11 = y1c*32 + x1c;
    sBc[n][d][0] = wx0*wy0*((vx0 && vy0) ? mask[n*XH + p00] : 0.f);
    sBc[n][d][1] = wx1*wy0*((vx1 && vy0) ? mask[n*XH + p10] : 0.f);
    sBc[n][d][2] = wx0*wy1*((vx0 && vy1) ? mask[n*XH + p01] : 0.f);
    sBc[n][d][3] = wx1*wy1*((vx1 && vy1) ? mask[n*XH + p11] : 0.f);
    sBp[n][d][0] = p00; sBp[n][d][1] = p10; sBp[n][d][2] = p01; sBp[n][d][3] = p11;
  }
  if (tid >= 256) {
    // sAt: xyz_iv_enc[view 0] . Wv slice (needs only sPv[0], sWv)
    int t = tid - 256;
    int d = t >> 3, sub = t & 7;
    float p = 0.f;
    for (int kk = sub * 12; kk < sub * 12 + 12; ++kk) {
      int comp = kk >> 5, idx = kk & 31;
      float ang = sPv[0][d][comp] * (float)(1 << (idx & 15));
      float ev = (idx < 16) ? __sinf(ang) : __cosf(ang);
      p += ev * sWv[128 + kk];
    }
    if (sub == 0)
      for (int j = 0; j < 3; ++j) p += sPv[0][d][j] * sWv[224 + j];
    #pragma unroll
    for (int o = 1; o < 8; o <<= 1) p += __shfl_xor(p, o);
    if (sub == 0) sAt[d] = p;
  }
  __syncthreads();   // B3

  // build-thread constants: lds row = d*4 + n
  const int brow = tid >> 2;            // 0..127
  const int bn = brow & 3, bd = brow >> 2;
  const int kloc0 = (tid & 3) * 16;     // k offset within row
  float plog = 0.f;                     // logit partial (kq 0..127)

  // ======= MERGED phase: gather (loads first) + sEnc2/sBt trig + pack =======
  {
    const float* bc = sBc[bn][bd];
    const int*   bp = sBp[bn][bd];
    const float* xb = xref + bn * XH * XC;

    // -- issue chunk-0 q=0,1 loads early (latency hides under trig below) --
    float4 pf[8];
    #pragma unroll
    for (int qq = 0; qq < 2; ++qq) {
      pf[qq*4+0] = *(const float4*)(xb + bp[0] * XC + kloc0 + 4 * qq);
      pf[qq*4+1] = *(const float4*)(xb + bp[1] * XC + kloc0 + 4 * qq);
      pf[qq*4+2] = *(const float4*)(xb + bp[2] * XC + kloc0 + 4 * qq);
      pf[qq*4+3] = *(const float4*)(xb + bp[3] * XC + kloc0 + 4 * qq);
    }

    // -- sEnc2 fill (all 512 threads; deps sPlk/sDiv ready at B3) --
    {
      int n = tid >> 7, off = tid & 127;
      float val = 0.f;
      if (off >= 3 && off < 99) {
        int kk = off - 3;                       // cam_iv_enc index
        int comp = kk >> 4, idx = kk & 15;
        float ang = sPlk[n][comp] * (float)(1 << (idx & 7));
        val = (idx < 8) ? __sinf(ang) : __cosf(ang);
      } else if (off >= 99 && off < 102) {
        val = sDiv[n + 1][off - 99];
      }
      sEnc2[n][off] = f2b(val);
    }
    // -- sBt (threads 256..287; deps sOtg ready at B3) --
    if (tid >= 256 && tid < 288) {
      int t = tid - 256, n = t >> 3, sub = t & 7;
      float p = 0.f;
      for (int kk = sub * 12; kk < sub * 12 + 12; ++kk) {
        int comp = kk >> 5, idx = kk & 31;
        float ang = sOtg[n][comp] * (float)(1 << (idx & 15));
        float ev = (idx < 16) ? __sinf(ang) : __cosf(ang);
        p += ev * sWv[230 + kk];
      }
      if (sub == 0) {
        for (int j = 0; j < 3; ++j) p += sOtg[n][j] * sWv[227 + j];
        p += bvp[0];
      }
      #pragma unroll
      for (int o = 1; o < 8; o <<= 1) p += __shfl_xor(p, o);
      if (sub == 0) sBt[n] = p;
    }

    // -- chunk 0 blend/pack (q<2 from prefetch regs) --
    {
      int kg = kloc0;
      float vv[16];
      #pragma unroll
      for (int qq = 0; qq < 4; ++qq) {
        float4 a0, a1, a2, a3;
        if (qq < 2) {
          a0 = pf[qq*4+0]; a1 = pf[qq*4+1]; a2 = pf[qq*4+2]; a3 = pf[qq*4+3];
        } else {
          a0 = *(const float4*)(xb + bp[0] * XC + kg + 4 * qq);
          a1 = *(const float4*)(xb + bp[1] * XC + kg + 4 * qq);
          a2 = *(const float4*)(xb + bp[2] * XC + kg + 4 * qq);
          a3 = *(const float4*)(xb + bp[3] * XC + kg + 4 * qq);
        }
        #pragma unroll
        for (int j = 0; j < 4; ++j)
          vv[4 * qq + j] = bc[0]*(&a0.x)[j] + bc[1]*(&a1.x)[j]
                         + bc[2]*(&a2.x)[j] + bc[3]*(&a3.x)[j];
      }
      #pragma unroll
      for (int j = 0; j < 16; ++j) plog += vv[j] * sWv[kg + j];
      #pragma unroll
      for (int qq = 0; qq < 2; ++qq) {
        unsigned ph[4], pl[4];
        #pragma unroll
        for (int j = 0; j < 4; ++j) {
          float v0 = vv[8 * qq + 2 * j], v1 = vv[8 * qq + 2 * j + 1];
          unsigned hp = pk2bf(v0, v1);
          float r0 = v0 - b2f((unsigned short)(hp & 0xFFFF));
          float r1 = v1 - b2f((unsigned short)(hp >> 16));
          ph[j] = hp;
          pl[j] = pk2bf(r0, r1);
        }
        int gidx = (brow * 128 + kg + 8 * qq) ^ ((brow & 7) << 3);
        *(uint4*)&sFcHi[gidx] = *(uint4*)ph;
        *(uint4*)&sFcLo[gidx] = *(uint4*)pl;
      }
    }
    // -- chunk 1 (loads + blend/pack) --
    {
      int kg = 64 + kloc0;
      float vv[16];
      #pragma unroll
      for (int qq = 0; qq < 4; ++qq) {
        float4 a0 = *(const float4*)(xb + bp[0] * XC + kg + 4 * qq);
        float4 a1 = *(const float4*)(xb + bp[1] * XC + kg + 4 * qq);
        float4 a2 = *(const float4*)(xb + bp[2] * XC + kg + 4 * qq);
        float4 a3 = *(const float4*)(xb + bp[3] * XC + kg + 4 * qq);
        #pragma unroll
        for (int j = 0; j < 4; ++j)
          vv[4 * qq + j] = bc[0]*(&a0.x)[j] + bc[1]*(&a1.x)[j]
                         + bc[2]*(&a2.x)[j] + bc[3]*(&a3.x)[j];
      }
      #pragma unroll
      for (int j = 0; j < 16; ++j) plog += vv[j] * sWv[kg + j];
      #pragma unroll
      for (int qq = 0; qq < 2; ++qq) {
        unsigned ph[4], pl[4];
        #pragma unroll
        for (int j = 0; j < 4; ++j) {
          float v0 = vv[8 * qq + 2 * j], v1 = vv[8 * qq + 2 * j + 1];
          unsigned hp = pk2bf(v0, v1);
          float r0 = v0 - b2f((unsigned short)(hp & 0xFFFF));
          float r1 = v1 - b2f((unsigned short)(hp >> 16));
          ph[j] = hp;
          pl[j] = pk2bf(r0, r1);
        }
        int gidx = (brow * 128 + kg + 8 * qq) ^ ((brow & 7) << 3);
        *(uint4*)&sFcHi[gidx] = *(uint4*)ph;
        *(uint4*)&sFcLo[gidx] = *(uint4*)pl;
      }
    }
    // logit partial reduce (4 threads per (n,d))
    {
      float p = plog;
      p += __shfl_xor(p, 1);
      p += __shfl_xor(p, 2);
      if ((tid & 3) == 0) sLogit[bn][bd] = p;
    }
  }
  __syncthreads();   // B4: sFc + sLogit + sEnc2 + sBt ready

  // ---- softmax over n (wave 0 lanes 0..31; runs while others MFMA) ----
  if (tid < 32) {
    int d = tid;
    float l0 = sLogit[0][d] + sAt[d] + sBt[0];
    float l1 = sLogit[1][d] + sAt[d] + sBt[1];
    float l2 = sLogit[2][d] + sAt[d] + sBt[2];
    float l3 = sLogit[3][d] + sAt[d] + sBt[3];
    float m = fmaxf(fmaxf(l0, l1), fmaxf(l2, l3));
    float e0 = __expf(l0 - m), e1 = __expf(l1 - m), e2 = __expf(l2 - m), e3 = __expf(l3 - m);
    float inv = 1.f / (e0 + e1 + e2 + e3);
    float w0 = e0*inv, w1 = e1*inv, w2 = e2*inv, w3 = e3*inv;
    sAw[0][d] = w0; sAw[1][d] = w1; sAw[2][d] = w2; sAw[3][d] = w3;
    out1[(0*XH + h)*XD + d] = w0;
    out1[(1*XH + h)*XD + d] = w1;
    out1[(2*XH + h)*XD + d] = w2;
    out1[(3*XH + h)*XD + d] = w3;
  }

  // ---- wave decomposition for GEMM1: M=128 rows (row = d*4 + n) ----
  const int w = tid >> 6, lane = tid & 63;
  const int rt = w & 3, cg = w >> 2;
  const int lrow = lane & 15, lg = lane >> 4;
  float bias1[4];
  #pragma unroll
  for (int ct = 0; ct < 4; ++ct) bias1[ct] = b1p[cg * 64 + ct * 16 + lrow];

  f32x4 acc1[2][4];
  #pragma unroll
  for (int rf = 0; rf < 2; ++rf)
    #pragma unroll
    for (int ct = 0; ct < 4; ++ct) acc1[rf][ct] = (f32x4){0.f, 0.f, 0.f, 0.f};

  // ======= GEMM1: interleaved A (LDS, kq 0..127) + B (reg, kq 128..351) =======
  {
    const int r0 = rt * 32 + lrow;
    const int nn = r0 & 3;               // same n for both rows
    const int dd = r0 >> 2;              // row1 has d = dd+4
    const float* pv0 = sPv[nn + 1][dd];
    const float* pv1 = sPv[nn + 1][dd + 4];
    const unsigned short* enc = sEnc2[nn];
    const float m0 = (lg & 1) ? 256.f : 1.f;
    const bool usn = (lg < 2);

    // part-A step: LDS reads + 24 MFMAs against wfrag kc=sk
    auto stepA = [&](int sk) {
      const int ai0 = (r0 * 128 + sk * 32 + 8 * lg) ^ ((r0 & 7) << 3);
      const int ai1 = ai0 + 16 * 128;    // r1 = r0+16: same (r&7) swizzle
      bf16x8 ah0 = *(const bf16x8*)&sFcHi[ai0];
      bf16x8 ah1 = *(const bf16x8*)&sFcHi[ai1];
      bf16x8 al0 = *(const bf16x8*)&sFcLo[ai0];
      bf16x8 al1 = *(const bf16x8*)&sFcLo[ai1];
      const bf16x8* wkh = wfrag + (sk * 8 + cg * 4) * 64 + lane;
      const bf16x8* wkl = wkh + WT1;
      #pragma unroll
      for (int ct = 0; ct < 4; ++ct) {
        bf16x8 bh = wkh[ct * 64];
        bf16x8 bl = wkl[ct * 64];
        acc1[0][ct] = __builtin_amdgcn_mfma_f32_16x16x32_bf16(ah0, bh, acc1[0][ct], 0, 0, 0);
        acc1[0][ct] = __builtin_amdgcn_mfma_f32_16x16x32_bf16(ah0, bl, acc1[0][ct], 0, 0, 0);
        acc1[0][ct] = __builtin_amdgcn_mfma_f32_16x16x32_bf16(al0, bh, acc1[0][ct], 0, 0, 0);
        acc1[1][ct] = __builtin_amdgcn_mfma_f32_16x16x32_bf16(ah1, bh, acc1[1][ct], 0, 0, 0);
        acc1[1][ct] = __builtin_amdgcn_mfma_f32_16x16x32_bf16(ah1, bl, acc1[1][ct], 0, 0, 0);
        acc1[1][ct] = __builtin_amdgcn_mfma_f32_16x16x32_bf16(al1, bh, acc1[1][ct], 0, 0, 0);
      }
    };
    // part-B step: 16 MFMAs against wfrag kc
    auto stepB = [&](int kc, bf16x8 A0, bf16x8 A1) {
      const bf16x8* wkh = wfrag + (kc * 8 + cg * 4) * 64 + lane;
      const bf16x8* wkl = wkh + WT1;
      #pragma unroll
      for (int ct = 0; ct < 4; ++ct) {
        bf16x8 bh = wkh[ct * 64];
        bf16x8 bl = wkl[ct * 64];
        acc1[0][ct] = __builtin_amdgcn_mfma_f32_16x16x32_bf16(A0, bh, acc1[0][ct], 0, 0, 0);
        acc1[0][ct] = __builtin_amdgcn_mfma_f32_16x16x32_bf16(A0, bl, acc1[0][ct], 0, 0, 0);
        acc1[1][ct] = __builtin_amdgcn_mfma_f32_16x16x32_bf16(A1, bh, acc1[1][ct], 0, 0, 0);
        acc1[1][ct] = __builtin_amdgcn_mfma_f32_16x16x32_bf16(A1, bl, acc1[1][ct], 0, 0, 0);
      }
    };
    // trig frag: element j has idx2 = lg*8+j in [0,32): scale 2^((lg&1)*8+j)
    auto trigf = [&](const float* pv, int comp) -> bf16x8 {
      float pA = pv[comp] * m0;
      unsigned ph[4];
      #pragma unroll
      for (int mj = 0; mj < 4; ++mj) {
        float a0f = pA * (float)(1 << (2 * mj));
        float a1f = pA * (float)(1 << (2 * mj + 1));
        float v0 = usn ? __sinf(a0f) : __cosf(a0f);
        float v1 = usn ? __sinf(a1f) : __cosf(a1f);
        ph[mj] = pk2bf(v0, v1);
      }
      union { unsigned u[4]; bf16x8 f; } cv;
      cv.u[0] = ph[0]; cv.u[1] = ph[1]; cv.u[2] = ph[2]; cv.u[3] = ph[3];
      return cv.f;
    };
    auto encf = [&](int off) -> bf16x8 {
      return *(const bf16x8*)&enc[off + lg * 8];
    };

    // interleaved super-steps: trig VALU sits between A's loads and MFMAs
    {
      bf16x8 t0 = trigf(pv0, 0), t1 = trigf(pv1, 0);
      stepA(0); stepB(4, t0, t1);
    }
    {
      bf16x8 t0 = trigf(pv0, 1), t1 = trigf(pv1, 1);
      stepA(1); stepB(5, t0, t1);
    }
    {
      bf16x8 t0 = trigf(pv0, 2), t1 = trigf(pv1, 2);
      stepA(2); stepB(6, t0, t1);
    }
    {
      bf16x8 e0 = encf(0);
      bf16x8 e1 = e0;
      if (lg == 0) {   // kq 224..226: raw xyz_iv (d-dependent)
        e0[0] = (short)f2b(pv0[0]); e0[1] = (short)f2b(pv0[1]); e0[2] = (short)f2b(pv0[2]);
        e1[0] = (short)f2b(pv1[0]); e1[1] = (short)f2b(pv1[1]); e1[2] = (short)f2b(pv1[2]);
      }
      stepA(3); stepB(7, e0, e1);
    }
    { bf16x8 e = encf(32); stepB(8, e, e); }
    { bf16x8 e = encf(64); stepB(9, e, e); }
    { bf16x8 e = encf(96); stepB(10, e, e); }
  }
  __syncthreads();   // B5: sAw visible; all sFc reads done

  // ======= thread-local blend: hb[d][c] = sum_i aw[i][d]*silu(acc[i]) =======
  // acc1[rf][ct][i]: row = tile*16 + lg*4 + i -> d = (rt*2+rf)*4 + lg, view = i.
  #pragma unroll
  for (int rf = 0; rf < 2; ++rf) {
    int d = (rt * 2 + rf) * 4 + lg;
    float a0 = sAw[0][d], a1 = sAw[1][d], a2 = sAw[2][d], a3 = sAw[3][d];
    #pragma unroll
    for (int ct = 0; ct < 4; ++ct) {
      int c = cg * 64 + ct * 16 + lrow;
      float x0 = acc1[rf][ct][0] + bias1[ct];
      float x1 = acc1[rf][ct][1] + bias1[ct];
      float x2 = acc1[rf][ct][2] + bias1[ct];
      float x3 = acc1[rf][ct][3] + bias1[ct];
      float hb = a0 * __fdividef(x0, 1.f + __expf(-x0))
               + a1 * __fdividef(x1, 1.f + __expf(-x1))
               + a2 * __fdividef(x2, 1.f + __expf(-x2))
               + a3 * __fdividef(x3, 1.f + __expf(-x3));
      unsigned short hh = f2b(hb);
      unsigned short hl = f2b(hb - b2f(hh));
      int idx = (d * 128 + c) ^ ((d & 7) << 3);
      sHbHi[idx] = hh; sHbLo[idx] = hl;
    }
  }
  __syncthreads();   // B6

  // ======= GEMM2 (split): fused = hb @ W2 + b2  (M=32) =======
  const int rt2 = w & 1, cg2 = w >> 1;
  float bias2[2], wdv[2];
  #pragma unroll
  for (int cti = 0; cti < 2; ++cti) {
    int c = cg2 * 32 + cti * 16 + lrow;
    bias2[cti] = b2p[c]; wdv[cti] = Wdp[c];
  }
  f32x4 acc2[2];
  acc2[0] = (f32x4){0.f, 0.f, 0.f, 0.f};
  acc2[1] = (f32x4){0.f, 0.f, 0.f, 0.f};
  {
    const int ar = rt2 * 16 + lrow;
    #pragma unroll
    for (int kc = 0; kc < 4; ++kc) {
      int aidx = (ar * 128 + kc * 32 + 8 * lg) ^ ((ar & 7) << 3);
      bf16x8 ah = *(const bf16x8*)&sHbHi[aidx];
      bf16x8 al = *(const bf16x8*)&sHbLo[aidx];
      const bf16x8* wkh = wfrag + 2 * WT1 + (kc * 8 + cg2 * 2) * 64 + lane;
      const bf16x8* wkl = wkh + WT2;
      #pragma unroll
      for (int cti = 0; cti < 2; ++cti) {
        bf16x8 bh = wkh[cti * 64];
        bf16x8 bl = wkl[cti * 64];
        acc2[cti] = __builtin_amdgcn_mfma_f32_16x16x32_bf16(ah, bh, acc2[cti], 0, 0, 0);
        acc2[cti] = __builtin_amdgcn_mfma_f32_16x16x32_bf16(ah, bl, acc2[cti], 0, 0, 0);
        acc2[cti] = __builtin_amdgcn_mfma_f32_16x16x32_bf16(al, bh, acc2[cti], 0, 0, 0);
      }
    }
  }

  // ======= epilogue: stage fused (+out col) in LDS, then full-line writes =======
  {
    float part[4] = {0.f, 0.f, 0.f, 0.f};
    #pragma unroll
    for (int cti = 0; cti < 2; ++cti) {
      int c = cg2 * 32 + cti * 16 + lrow;
      #pragma unroll
      for (int i = 0; i < 4; ++i) {
        int d = rt2 * 16 + lg * 4 + i;
        float fv = acc2[cti][i] + bias2[cti];
        sOut[d * 129 + c] = fv;
        part[i] += fv * wdv[cti];
      }
    }
    #pragma unroll
    for (int i = 0; i < 4; ++i) {
      float p = part[i];
      #pragma unroll
      for (int o = 1; o < 16; o <<= 1) p += __shfl_xor(p, o);
      if (lrow == 0) sOutPart[cg2][rt2 * 16 + lg * 4 + i] = p;
    }
  }
  __syncthreads();   // B7
  if (tid < 32)
    sOut[tid * 129 + 128] =
      sOutPart[0][tid] + sOutPart[1][tid] + sOutPart[2][tid] + sOutPart[3][tid];
  __syncthreads();   // B8
  {
    // per-block out0 slice is contiguous: 32*129*4 = 16512 B = 258 full lines,
    // h*16512 is 64B-aligned -> zero partial-line RMW.
    const float4* src = (const float4*)sOut;
    float4* dst = (float4*)(out0 + (size_t)h * (XD * 129));
    for (int i = tid; i < (XD * 129) / 4; i += 512) dst[i] = src[i];
  }
}

extern "C" void kernel_launch(void* const* d_in, const int* in_sizes, int n_in,
                              void* d_out, int out_size, void* d_ws, size_t ws_size,
                              hipStream_t stream) {
  const float* xref = (const float*)d_in[0];
  const float* mask = (const float*)d_in[1];
  const float* rpts = (const float*)d_in[2];
  const float* rays = (const float*)d_in[3];
  const float* Rm   = (const float*)d_in[4];
  const float* Tm   = (const float*)d_in[5];
  const float* foc  = (const float*)d_in[6];
  const float* W1   = (const float*)d_in[7];
  const float* b1   = (const float*)d_in[8];
  const float* W2   = (const float*)d_in[9];
  const float* b2   = (const float*)d_in[10];
  const float* Wv   = (const float*)d_in[11];
  const float* bv   = (const float*)d_in[12];
  const float* Wd   = (const float*)d_in[13];
  float* out0 = (float*)d_out;
  float* out1 = out0 + (size_t)XH * XD * 129;

  hipLaunchKernelGGL(prep_frags, dim3(32), dim3(256), 0, stream,
                     W1, W2, (unsigned int*)d_ws);
  hipLaunchKernelGGL(nerf_main, dim3(XH), dim3(512), 0, stream,
                     xref, mask, rpts, rays, Rm, Tm, foc,
                     b1, b2, Wv, bv, Wd, (const bf16x8*)d_ws, out0, out1);
}